// Round 13
// baseline (113.300 us; speedup 1.0000x reference)
//
#include <hip/hip_runtime.h>
#include <hip/hip_fp16.h>

// Sizes (static, from reference)
#define NSUB 65536
#define NV0 10242
#define NV1 40962
#define NV2 163842
#define EPSV 1e-5f
#define SPLITK 16

__device__ inline float wave_red(float v) {
#pragma unroll
    for (int off = 32; off > 0; off >>= 1) v += __shfl_down(v, off, 64);
    return v;
}

// Block-reduce vals[16] ([c]=sum, [8+c]=sumsq, c<NCH) -> atomicAdd into slot.
template <int NCH>
__device__ inline void emit_stats(const float* vals, float* __restrict__ slot,
                                  float* stl /*shared [64]*/) {
    int t = threadIdx.x;
    float r[2 * NCH];
#pragma unroll
    for (int c = 0; c < NCH; ++c) {
        r[c] = wave_red(vals[c]);
        r[NCH + c] = wave_red(vals[8 + c]);
    }
    if ((t & 63) == 0) {
#pragma unroll
        for (int i = 0; i < 2 * NCH; ++i) stl[(t >> 6) * 16 + i] = r[i];
    }
    __syncthreads();
    if (t < 2 * NCH) {
        float v = stl[t] + stl[16 + t] + stl[32 + t] + stl[48 + t];
        int idx = (t < NCH) ? t : 8 + (t - NCH);
        atomicAdd(slot + idx, v);
    }
}

// Consumer prologue: BN scale/shift from raw sums. sS[c]=scale, sS[8+c]=shift.
template <int NCH>
__device__ inline void bn_from_sums(const float* __restrict__ slot, float n,
                                    const float* __restrict__ g,
                                    const float* __restrict__ b, float* sS) {
    int t = threadIdx.x;
    if (t < NCH) {
        float m = slot[t] / n;
        float var = slot[8 + t] / n - m * m;
        float scale = rsqrtf(var + EPSV) * g[t];
        sS[t] = scale;
        sS[8 + t] = b[t] - m * scale;
    }
}

// ---------------------------------------------------------------------------
// gemv1 split-K partials; block 0 zeroes stat slots (stream-order visible).
__global__ __launch_bounds__(256) void k_gemv1(const float* __restrict__ sub,
                                               const float* __restrict__ Ws,
                                               float* __restrict__ y1p,
                                               float* __restrict__ slots) {
    int task = blockIdx.x, o = task >> 4, s = task & (SPLITK - 1);
    int t = threadIdx.x;
    if (task == 0 && t < 80) slots[t] = 0.f;
    const float* row = Ws + (size_t)o * NSUB + s * (NSUB / SPLITK);
    const float* sb = sub + s * (NSUB / SPLITK);
    int i0 = t * 4, i1 = (256 + t) * 4, i2 = (512 + t) * 4, i3 = (768 + t) * 4;
    float4 xa = *(const float4*)(sb + i0), wa = *(const float4*)(row + i0);
    float4 xb = *(const float4*)(sb + i1), wb = *(const float4*)(row + i1);
    float4 xc = *(const float4*)(sb + i2), wc = *(const float4*)(row + i2);
    float4 xd = *(const float4*)(sb + i3), wd = *(const float4*)(row + i3);
    float a0 = xa.x * wa.x + xa.y * wa.y + xa.z * wa.z + xa.w * wa.w;
    float a1 = xb.x * wb.x + xb.y * wb.y + xb.z * wb.z + xb.w * wb.w;
    float a2 = xc.x * wc.x + xc.y * wc.y + xc.z * wc.z + xc.w * wc.w;
    float a3 = xd.x * wd.x + xd.y * wd.y + xd.z * wd.z + xd.w * wd.w;
    float acc = wave_red((a0 + a1) + (a2 + a3));
    __shared__ float red[4];
    if ((t & 63) == 0) red[t >> 6] = acc;
    __syncthreads();
    if (t == 0) y1p[s * 256 + o] = red[0] + red[1] + red[2] + red[3];
}

// ---------------------------------------------------------------------------
// gemv2: rebuild y1 in LDS from y1p + b_sub, 4 outputs per wave.
__global__ __launch_bounds__(256) void k_gemv2(const float* __restrict__ bs,
                                               const float* __restrict__ y1p,
                                               const float* __restrict__ Wf,
                                               const float* __restrict__ bfc,
                                               float* __restrict__ x0) {
    __shared__ float sy[256];
    int t = threadIdx.x;
    float acc = bs[t];
#pragma unroll
    for (int s = 0; s < SPLITK; ++s) acc += y1p[s * 256 + t];
    sy[t] = acc;
    __syncthreads();
    int wv = t >> 6, ln = t & 63;
    float4 y4 = *(const float4*)(sy + ln * 4);
    int obase = (blockIdx.x * 4 + wv) * 4;
#pragma unroll
    for (int r = 0; r < 4; ++r) {
        int o = obase + r;
        if (o < 3 * NV0) {
            const float* row = Wf + (size_t)o * 256;
            float4 w4 = *(const float4*)(row + ln * 4);
            float d = wave_red(w4.x * y4.x + w4.y * y4.y + w4.z * y4.z + w4.w * y4.w);
            if (ln == 0) x0[o] = d + bfc[o];
        }
    }
}

// ---------------------------------------------------------------------------
// upconv. IN_HALF: xin is padded half4 (stride 4); else fp32 (stride 3).
// OWN_STATS: per-block redundant scan of fp32 xin. Output: padded half4.
template <bool IN_HALF, bool OWN_STATS>
__global__ __launch_bounds__(256) void k_upconv(const void* __restrict__ xin_, int nIn, int nOut,
                                                const float* __restrict__ slotIn,
                                                float* __restrict__ slotOut,
                                                const float* __restrict__ gIn,
                                                const float* __restrict__ bIn,
                                                const float* __restrict__ W,
                                                const float* __restrict__ bias,
                                                const int* __restrict__ top,
                                                const int* __restrict__ down,
                                                __half* __restrict__ xout) {
    const float* xf = (const float*)xin_;
    const __half* xh = (const __half*)xin_;
    __shared__ float sW[63], sB[21], sS[16], stl[64];
    int t = threadIdx.x;
    if (OWN_STATS) {
        if (t < 63) sW[t] = W[t];
        if (t >= 64 && t < 85) sB[t - 64] = bias[t - 64];
        float s[6] = {0.f, 0.f, 0.f, 0.f, 0.f, 0.f};
        for (int v = t; v < nIn; v += 256) {
            float a = xf[v * 3 + 0], b = xf[v * 3 + 1], c = xf[v * 3 + 2];
            s[0] += a; s[1] += b; s[2] += c;
            s[3] += a * a; s[4] += b * b; s[5] += c * c;
        }
#pragma unroll
        for (int i = 0; i < 6; ++i) s[i] = wave_red(s[i]);
        if ((t & 63) == 0) {
            int w = t >> 6;
#pragma unroll
            for (int i = 0; i < 6; ++i) stl[w * 8 + i] = s[i];
        }
        __syncthreads();
        if (t < 3) {
            float n = (float)nIn;
            float sum = stl[t] + stl[8 + t] + stl[16 + t] + stl[24 + t];
            float sq = stl[3 + t] + stl[11 + t] + stl[19 + t] + stl[27 + t];
            float m = sum / n;
            float var = sq / n - m * m;
            float scale = rsqrtf(var + EPSV) * gIn[t];
            sS[t] = scale;
            sS[8 + t] = bIn[t] - m * scale;
        }
    } else {
        if (t >= 64 && t < 127) sW[t - 64] = W[t - 64];
        if (t >= 128 && t < 149) sB[t - 128] = bias[t - 128];
        bn_from_sums<3>(slotIn, (float)nIn, gIn, bIn, sS);
    }
    __syncthreads();

    int v = blockIdx.x * 256 + t;
    bool ok = v < nOut;
    float o0 = 0.f, o1 = 0.f, o2 = 0.f;
    if (ok) {
        auto uval = [&](int idx, float* o3) {
            int src = idx / 7;
            int j = idx - src * 7;
            float x0v, x1v, x2v;
            if (IN_HALF) {
                union { uint2 u; __half h[4]; } g;
                g.u = *(const uint2*)(xh + (size_t)src * 4);
                x0v = __half2float(g.h[0]);
                x1v = __half2float(g.h[1]);
                x2v = __half2float(g.h[2]);
            } else {
                x0v = xf[src * 3 + 0]; x1v = xf[src * 3 + 1]; x2v = xf[src * 3 + 2];
            }
            float a0 = x0v * sS[0] + sS[8];  a0 = a0 > 0.f ? a0 : 0.2f * a0;
            float a1 = x1v * sS[1] + sS[9];  a1 = a1 > 0.f ? a1 : 0.2f * a1;
            float a2 = x2v * sS[2] + sS[10]; a2 = a2 > 0.f ? a2 : 0.2f * a2;
#pragma unroll
            for (int c = 0; c < 3; ++c) {
                int rr = j * 3 + c;
                o3[c] = sB[rr] + a0 * sW[rr * 3 + 0] + a1 * sW[rr * 3 + 1] + a2 * sW[rr * 3 + 2];
            }
        };
        if (v < nIn) {
            float o3[3];
            uval(top[v], o3);
            o0 = o3[0]; o1 = o3[1]; o2 = o3[2];
        } else {
            int i = v - nIn;
            float a[3], bb[3];
            uval(down[2 * i], a);
            uval(down[2 * i + 1], bb);
            o0 = 0.5f * (a[0] + a[1]);
            o1 = 0.5f * (a[2] + bb[0]);
            o2 = 0.5f * (bb[1] + bb[2]);
        }
        union { __half h[4]; uint2 u; } pk;
        pk.h[0] = __float2half(o0); pk.h[1] = __float2half(o1);
        pk.h[2] = __float2half(o2); pk.h[3] = __float2half(0.f);
        *(uint2*)(xout + (size_t)v * 4) = pk.u;
    }
    float vals[16];
#pragma unroll
    for (int i = 0; i < 16; ++i) vals[i] = 0.f;
    vals[0] = o0; vals[1] = o1; vals[2] = o2;
    vals[8] = o0 * o0; vals[9] = o1 * o1; vals[10] = o2 * o2;
    emit_stats<3>(vals, slotOut, stl);
}

// ---------------------------------------------------------------------------
// one-ring conv, 2 THREADS PER VERTEX (even lane: neighbors 0-3 + bias,
// odd lane: neighbors 4-6; combine via shfl_xor). Block covers 128 vertices.
// CIN=3 -> stride-4 half (8B gather); CIN=8 -> stride-8 half (16B gather).
template <int CIN, int COUT, bool EMIT>
__global__ __launch_bounds__(256) void k_onering(const __half* __restrict__ xin,
                                                 const float* __restrict__ slotIn,
                                                 float* __restrict__ slotOut,
                                                 const float* __restrict__ gIn,
                                                 const float* __restrict__ bIn,
                                                 const float* __restrict__ W,
                                                 const float* __restrict__ bias,
                                                 const int* __restrict__ neigh,
                                                 __half* __restrict__ outH,
                                                 float* __restrict__ outF) {
    __shared__ float sW[COUT * 7 * CIN], sB[COUT], sS[16], stl[64];
    int t = threadIdx.x;
    for (int i = t; i < COUT * 7 * CIN; i += 256) sW[i] = W[i];
    if (t >= 32 && t < 32 + COUT) sB[t - 32] = bias[t - 32];
    bn_from_sums<CIN>(slotIn, (float)NV2, gIn, bIn, sS);
    __syncthreads();

    int half = t & 1;
    int v = blockIdx.x * 128 + (t >> 1);
    bool ok = v < NV2;

    float acc[COUT];
#pragma unroll
    for (int c = 0; c < COUT; ++c) acc[c] = 0.f;
    if (ok) {
        if (!half) {
#pragma unroll
            for (int c = 0; c < COUT; ++c) acc[c] = sB[c];
        }
        const int* np = neigh + (size_t)v * 7;
        int jbeg = half ? 4 : 0;
        int jend = half ? 7 : 4;
        for (int j = jbeg; j < jend; ++j) {
            int nb = np[j];
            float tv[CIN];
            if (CIN == 8) {
                union { uint4 u; __half h[8]; } g;
                g.u = *(const uint4*)(xin + (size_t)nb * 8);
#pragma unroll
                for (int k = 0; k < 8; ++k) {
                    float x = __half2float(g.h[k]) * sS[k] + sS[8 + k];
                    tv[k] = x > 0.f ? x : 0.2f * x;
                }
            } else {
                union { uint2 u; __half h[4]; } g;
                g.u = *(const uint2*)(xin + (size_t)nb * 4);
#pragma unroll
                for (int k = 0; k < CIN; ++k) {
                    float x = __half2float(g.h[k]) * sS[k] + sS[8 + k];
                    tv[k] = x > 0.f ? x : 0.2f * x;
                }
            }
#pragma unroll
            for (int c = 0; c < COUT; ++c) {
                float a = acc[c];
#pragma unroll
                for (int k = 0; k < CIN; ++k) a += tv[k] * sW[c * 7 * CIN + j * CIN + k];
                acc[c] = a;
            }
        }
    }
    // combine pair (lanes 2k, 2k+1 share a wave)
#pragma unroll
    for (int c = 0; c < COUT; ++c) acc[c] += __shfl_xor(acc[c], 1, 64);

    if (ok && !half) {
        if (COUT == 8) {
            union { __half h[8]; uint4 u; } pk;
#pragma unroll
            for (int c = 0; c < 8; ++c) pk.h[c] = __float2half(acc[c]);
            *(uint4*)(outH + (size_t)v * 8) = pk.u;
        } else {
            outF[(size_t)v * COUT + 0] = acc[0];
            outF[(size_t)v * COUT + 1] = acc[1];
        }
    }
    if (EMIT) {
        float vals[16];
#pragma unroll
        for (int i = 0; i < 16; ++i) vals[i] = 0.f;
        bool count = ok && !half;   // one contribution per vertex
#pragma unroll
        for (int c = 0; c < COUT; ++c) {
            float a = count ? acc[c] : 0.f;
            vals[c] = a;
            vals[8 + c] = a * a;
        }
        emit_stats<COUT>(vals, slotOut, stl);
    }
}

// ---------------------------------------------------------------------------
extern "C" void kernel_launch(void* const* d_in, const int* in_sizes, int n_in,
                              void* d_out, int out_size, void* d_ws, size_t ws_size,
                              hipStream_t stream) {
    const float* sub_id = (const float*)d_in[0];
    const float* W_sub  = (const float*)d_in[1];
    const float* b_sub  = (const float*)d_in[2];
    const float* W_fc   = (const float*)d_in[3];
    const float* b_fc   = (const float*)d_in[4];
    const float* bn_u0g = (const float*)d_in[5];
    const float* bn_u0b = (const float*)d_in[6];
    const float* up0_W  = (const float*)d_in[7];
    const float* up0_b  = (const float*)d_in[8];
    const float* bn_u1g = (const float*)d_in[9];
    const float* bn_u1b = (const float*)d_in[10];
    const float* up1_W  = (const float*)d_in[11];
    const float* up1_b  = (const float*)d_in[12];
    const float* bn0g   = (const float*)d_in[13];
    const float* bn0b   = (const float*)d_in[14];
    const float* c0_W   = (const float*)d_in[15];
    const float* c0_b   = (const float*)d_in[16];
    const float* bn1g   = (const float*)d_in[17];
    const float* bn1b   = (const float*)d_in[18];
    const float* c1_W   = (const float*)d_in[19];
    const float* c1_b   = (const float*)d_in[20];
    const float* bn2g   = (const float*)d_in[21];
    const float* bn2b   = (const float*)d_in[22];
    const float* c2_W   = (const float*)d_in[23];
    const float* c2_b   = (const float*)d_in[24];
    const int* neigh  = (const int*)d_in[25];
    const int* top0   = (const int*)d_in[26];
    const int* down0  = (const int*)d_in[27];
    const int* top1   = (const int*)d_in[28];
    const int* down1  = (const int*)d_in[29];

    float* ws = (float*)d_ws;
    // float-unit offsets; all 16B-aligned where vector-accessed
    float* y1p    = ws + 0;                   // 4096
    float* x0     = ws + 4096;                // 30726 fp32 -> ends 34822
    __half* xA_h  = (__half*)(ws + 34824);    // 40962*4 h = 81924 f -> ends 116748
    __half* xB_h  = (__half*)(ws + 116748);   // 163842*4 h = 327684 f -> ends 444432
    __half* h0_h  = (__half*)(ws + 444432);   // 163842*8 h = 655368 f -> ends 1099800
    __half* h1_h  = (__half*)(ws + 1099800);  // 163842*8 h = 655368 f -> ends 1755168
    float* slots  = ws + 1755168;             // 5*16

    float* st1 = slots + 16;
    float* st2 = slots + 32;
    float* st3 = slots + 48;
    float* st4 = slots + 64;

    const unsigned NB1 = (NV1 + 255) / 256;       // 161
    const unsigned NB2 = (NV2 + 255) / 256;       // 641
    const unsigned NBR = (NV2 + 127) / 128;       // 1281
    const unsigned NBG2 = (3 * NV0 + 15) / 16;    // 1921

    k_gemv1<<<256 * SPLITK, 256, 0, stream>>>(sub_id, W_sub, y1p, slots);
    k_gemv2<<<NBG2, 256, 0, stream>>>(b_sub, y1p, W_fc, b_fc, x0);

    k_upconv<false, true><<<NB1, 256, 0, stream>>>(x0, NV0, NV1, nullptr, st1,
                                                   bn_u0g, bn_u0b, up0_W, up0_b,
                                                   top0, down0, xA_h);
    k_upconv<true, false><<<NB2, 256, 0, stream>>>(xA_h, NV1, NV2, st1, st2,
                                                   bn_u1g, bn_u1b, up1_W, up1_b,
                                                   top1, down1, xB_h);

    k_onering<3, 8, true><<<NBR, 256, 0, stream>>>(
        xB_h, st2, st3, bn0g, bn0b, c0_W, c0_b, neigh, h0_h, nullptr);
    k_onering<8, 8, true><<<NBR, 256, 0, stream>>>(
        h0_h, st3, st4, bn1g, bn1b, c1_W, c1_b, neigh, h1_h, nullptr);
    k_onering<8, 2, false><<<NBR, 256, 0, stream>>>(
        h1_h, st4, nullptr, bn2g, bn2b, c2_W, c2_b, neigh, nullptr, (float*)d_out);
}

// Round 14
// 87.420 us; speedup vs baseline: 1.2960x; 1.2960x over previous
//
#include <hip/hip_runtime.h>
#include <hip/hip_fp16.h>

// Sizes (static, from reference)
#define NSUB 65536
#define NV0 10242
#define NV1 40962
#define NV2 163842
#define EPSV 1e-5f
#define SPLITK 16

__device__ inline float wave_red(float v) {
#pragma unroll
    for (int off = 32; off > 0; off >>= 1) v += __shfl_down(v, off, 64);
    return v;
}

// Block-reduce vals[16] ([c]=sum, [8+c]=sumsq, c<NCH) -> atomicAdd into slot.
template <int NCH>
__device__ inline void emit_stats(const float* vals, float* __restrict__ slot,
                                  float* stl /*shared [64]*/) {
    int t = threadIdx.x;
    float r[2 * NCH];
#pragma unroll
    for (int c = 0; c < NCH; ++c) {
        r[c] = wave_red(vals[c]);
        r[NCH + c] = wave_red(vals[8 + c]);
    }
    if ((t & 63) == 0) {
#pragma unroll
        for (int i = 0; i < 2 * NCH; ++i) stl[(t >> 6) * 16 + i] = r[i];
    }
    __syncthreads();
    if (t < 2 * NCH) {
        float v = stl[t] + stl[16 + t] + stl[32 + t] + stl[48 + t];
        int idx = (t < NCH) ? t : 8 + (t - NCH);
        atomicAdd(slot + idx, v);
    }
}

// Consumer prologue: BN scale/shift from raw sums. sS[c]=scale, sS[8+c]=shift.
template <int NCH>
__device__ inline void bn_from_sums(const float* __restrict__ slot, float n,
                                    const float* __restrict__ g,
                                    const float* __restrict__ b, float* sS) {
    int t = threadIdx.x;
    if (t < NCH) {
        float m = slot[t] / n;
        float var = slot[8 + t] / n - m * m;
        float scale = rsqrtf(var + EPSV) * g[t];
        sS[t] = scale;
        sS[8 + t] = b[t] - m * scale;
    }
}

// ---------------------------------------------------------------------------
// gemv1 split-K partials; block 0 zeroes slot region (80 + 256 bank floats).
__global__ __launch_bounds__(256) void k_gemv1(const float* __restrict__ sub,
                                               const float* __restrict__ Ws,
                                               float* __restrict__ y1p,
                                               float* __restrict__ slots) {
    int task = blockIdx.x, o = task >> 4, s = task & (SPLITK - 1);
    int t = threadIdx.x;
    if (task == 0) {
        for (int i = t; i < 336; i += 256) slots[i] = 0.f;
    }
    const float* row = Ws + (size_t)o * NSUB + s * (NSUB / SPLITK);
    const float* sb = sub + s * (NSUB / SPLITK);
    int i0 = t * 4, i1 = (256 + t) * 4, i2 = (512 + t) * 4, i3 = (768 + t) * 4;
    float4 xa = *(const float4*)(sb + i0), wa = *(const float4*)(row + i0);
    float4 xb = *(const float4*)(sb + i1), wb = *(const float4*)(row + i1);
    float4 xc = *(const float4*)(sb + i2), wc = *(const float4*)(row + i2);
    float4 xd = *(const float4*)(sb + i3), wd = *(const float4*)(row + i3);
    float a0 = xa.x * wa.x + xa.y * wa.y + xa.z * wa.z + xa.w * wa.w;
    float a1 = xb.x * wb.x + xb.y * wb.y + xb.z * wb.z + xb.w * wb.w;
    float a2 = xc.x * wc.x + xc.y * wc.y + xc.z * wc.z + xc.w * wc.w;
    float a3 = xd.x * wd.x + xd.y * wd.y + xd.z * wd.z + xd.w * wd.w;
    float acc = wave_red((a0 + a1) + (a2 + a3));
    __shared__ float red[4];
    if ((t & 63) == 0) red[t >> 6] = acc;
    __syncthreads();
    if (t == 0) y1p[s * 256 + o] = red[0] + red[1] + red[2] + red[3];
}

// ---------------------------------------------------------------------------
// gemv2: rebuild y1 in LDS, 4 outputs per wave, and emit x0 BN stats into
// a 16-bank slot region (bank = blockIdx & 15).
__global__ __launch_bounds__(256) void k_gemv2(const float* __restrict__ bs,
                                               const float* __restrict__ y1p,
                                               const float* __restrict__ Wf,
                                               const float* __restrict__ bfc,
                                               float* __restrict__ x0,
                                               float* __restrict__ bank0) {
    __shared__ float sy[256];
    __shared__ float stl[32];
    int t = threadIdx.x;
    float acc = bs[t];
#pragma unroll
    for (int s = 0; s < SPLITK; ++s) acc += y1p[s * 256 + t];
    sy[t] = acc;
    __syncthreads();
    int wv = t >> 6, ln = t & 63;
    float4 y4 = *(const float4*)(sy + ln * 4);
    int obase = (blockIdx.x * 4 + wv) * 4;
    float s3[3] = {0.f, 0.f, 0.f}, q3[3] = {0.f, 0.f, 0.f};
#pragma unroll
    for (int r = 0; r < 4; ++r) {
        int o = obase + r;
        if (o < 3 * NV0) {
            const float* row = Wf + (size_t)o * 256;
            float4 w4 = *(const float4*)(row + ln * 4);
            float d = wave_red(w4.x * y4.x + w4.y * y4.y + w4.z * y4.z + w4.w * y4.w);
            if (ln == 0) {
                float val = d + bfc[o];
                x0[o] = val;
                int ch = o % 3;
                s3[ch] += val;
                q3[ch] += val * val;
            }
        }
    }
    if (ln == 0) {
#pragma unroll
        for (int i = 0; i < 3; ++i) { stl[wv * 8 + i] = s3[i]; stl[wv * 8 + 3 + i] = q3[i]; }
    }
    __syncthreads();
    if (t < 6) {
        float v = stl[t] + stl[8 + t] + stl[16 + t] + stl[24 + t];
        int idx = (t < 3) ? t : 8 + (t - 3);
        atomicAdd(bank0 + (blockIdx.x & 15) * 16 + idx, v);
    }
}

// ---------------------------------------------------------------------------
// upconv. IN_HALF: xin is padded half4 (stride 4); else fp32 (stride 3).
// BANKED_IN: stats come from 16-bank region; else single 16-float slot.
// Output: padded half4 + fused output stats (single slot).
template <bool IN_HALF, bool BANKED_IN>
__global__ __launch_bounds__(256) void k_upconv(const void* __restrict__ xin_, int nIn, int nOut,
                                                const float* __restrict__ slotIn,
                                                float* __restrict__ slotOut,
                                                const float* __restrict__ gIn,
                                                const float* __restrict__ bIn,
                                                const float* __restrict__ W,
                                                const float* __restrict__ bias,
                                                const int* __restrict__ top,
                                                const int* __restrict__ down,
                                                __half* __restrict__ xout) {
    const float* xf = (const float*)xin_;
    const __half* xh = (const __half*)xin_;
    __shared__ float sW[63], sB[21], sS[16], stl[64];
    int t = threadIdx.x;
    if (t >= 64 && t < 127) sW[t - 64] = W[t - 64];
    if (t >= 128 && t < 149) sB[t - 128] = bias[t - 128];
    if (BANKED_IN) {
        if (t < 16) {
            float s = 0.f;
#pragma unroll
            for (int b = 0; b < 16; ++b) s += slotIn[b * 16 + t];
            stl[t] = s;
        }
        __syncthreads();
        if (t < 3) {
            float n = (float)nIn;
            float m = stl[t] / n;
            float var = stl[8 + t] / n - m * m;
            float scale = rsqrtf(var + EPSV) * gIn[t];
            sS[t] = scale;
            sS[8 + t] = bIn[t] - m * scale;
        }
    } else {
        bn_from_sums<3>(slotIn, (float)nIn, gIn, bIn, sS);
    }
    __syncthreads();

    int v = blockIdx.x * 256 + t;
    bool ok = v < nOut;
    float o0 = 0.f, o1 = 0.f, o2 = 0.f;
    if (ok) {
        auto uval = [&](int idx, float* o3) {
            int src = idx / 7;
            int j = idx - src * 7;
            float x0v, x1v, x2v;
            if (IN_HALF) {
                union { uint2 u; __half h[4]; } g;
                g.u = *(const uint2*)(xh + (size_t)src * 4);
                x0v = __half2float(g.h[0]);
                x1v = __half2float(g.h[1]);
                x2v = __half2float(g.h[2]);
            } else {
                x0v = xf[src * 3 + 0]; x1v = xf[src * 3 + 1]; x2v = xf[src * 3 + 2];
            }
            float a0 = x0v * sS[0] + sS[8];  a0 = a0 > 0.f ? a0 : 0.2f * a0;
            float a1 = x1v * sS[1] + sS[9];  a1 = a1 > 0.f ? a1 : 0.2f * a1;
            float a2 = x2v * sS[2] + sS[10]; a2 = a2 > 0.f ? a2 : 0.2f * a2;
#pragma unroll
            for (int c = 0; c < 3; ++c) {
                int rr = j * 3 + c;
                o3[c] = sB[rr] + a0 * sW[rr * 3 + 0] + a1 * sW[rr * 3 + 1] + a2 * sW[rr * 3 + 2];
            }
        };
        if (v < nIn) {
            float o3[3];
            uval(top[v], o3);
            o0 = o3[0]; o1 = o3[1]; o2 = o3[2];
        } else {
            int i = v - nIn;
            float a[3], bb[3];
            uval(down[2 * i], a);
            uval(down[2 * i + 1], bb);
            o0 = 0.5f * (a[0] + a[1]);
            o1 = 0.5f * (a[2] + bb[0]);
            o2 = 0.5f * (bb[1] + bb[2]);
        }
        union { __half h[4]; uint2 u; } pk;
        pk.h[0] = __float2half(o0); pk.h[1] = __float2half(o1);
        pk.h[2] = __float2half(o2); pk.h[3] = __float2half(0.f);
        *(uint2*)(xout + (size_t)v * 4) = pk.u;
    }
    float vals[16];
#pragma unroll
    for (int i = 0; i < 16; ++i) vals[i] = 0.f;
    vals[0] = o0; vals[1] = o1; vals[2] = o2;
    vals[8] = o0 * o0; vals[9] = o1 * o1; vals[10] = o2 * o2;
    emit_stats<3>(vals, slotOut, stl);
}

// ---------------------------------------------------------------------------
// one-ring conv on half inputs (round-12 form: 1 vertex/thread).
// CIN=3 -> stride-4 half (8B gather); CIN=8 -> stride-8 half (16B gather).
template <int CIN, int COUT, bool EMIT>
__global__ __launch_bounds__(256) void k_onering(const __half* __restrict__ xin,
                                                 const float* __restrict__ slotIn,
                                                 float* __restrict__ slotOut,
                                                 const float* __restrict__ gIn,
                                                 const float* __restrict__ bIn,
                                                 const float* __restrict__ W,
                                                 const float* __restrict__ bias,
                                                 const int* __restrict__ neigh,
                                                 __half* __restrict__ outH,
                                                 float* __restrict__ outF) {
    __shared__ float sW[COUT * 7 * CIN], sB[COUT], sS[16], stl[64];
    int t = threadIdx.x;
    for (int i = t; i < COUT * 7 * CIN; i += 256) sW[i] = W[i];
    if (t >= 32 && t < 32 + COUT) sB[t - 32] = bias[t - 32];
    bn_from_sums<CIN>(slotIn, (float)NV2, gIn, bIn, sS);
    __syncthreads();

    int v = blockIdx.x * 256 + t;
    bool ok = v < NV2;
    float acc[COUT];
#pragma unroll
    for (int c = 0; c < COUT; ++c) acc[c] = 0.f;
    if (ok) {
#pragma unroll
        for (int c = 0; c < COUT; ++c) acc[c] = sB[c];
        const int* np = neigh + (size_t)v * 7;
#pragma unroll
        for (int j = 0; j < 7; ++j) {
            int nb = np[j];
            float tv[CIN];
            if (CIN == 8) {
                union { uint4 u; __half h[8]; } g;
                g.u = *(const uint4*)(xin + (size_t)nb * 8);
#pragma unroll
                for (int k = 0; k < 8; ++k) {
                    float x = __half2float(g.h[k]) * sS[k] + sS[8 + k];
                    tv[k] = x > 0.f ? x : 0.2f * x;
                }
            } else {
                union { uint2 u; __half h[4]; } g;
                g.u = *(const uint2*)(xin + (size_t)nb * 4);
#pragma unroll
                for (int k = 0; k < CIN; ++k) {
                    float x = __half2float(g.h[k]) * sS[k] + sS[8 + k];
                    tv[k] = x > 0.f ? x : 0.2f * x;
                }
            }
#pragma unroll
            for (int c = 0; c < COUT; ++c) {
                float a = acc[c];
#pragma unroll
                for (int k = 0; k < CIN; ++k) a += tv[k] * sW[c * 7 * CIN + j * CIN + k];
                acc[c] = a;
            }
        }
        if (COUT == 8) {
            union { __half h[8]; uint4 u; } pk;
#pragma unroll
            for (int c = 0; c < 8; ++c) pk.h[c] = __float2half(acc[c]);
            *(uint4*)(outH + (size_t)v * 8) = pk.u;
        } else {
            outF[(size_t)v * COUT + 0] = acc[0];
            outF[(size_t)v * COUT + 1] = acc[1];
        }
    }
    if (EMIT) {
        float vals[16];
#pragma unroll
        for (int i = 0; i < 16; ++i) vals[i] = 0.f;
#pragma unroll
        for (int c = 0; c < COUT; ++c) { vals[c] = acc[c]; vals[8 + c] = acc[c] * acc[c]; }
        emit_stats<COUT>(vals, slotOut, stl);
    }
}

// ---------------------------------------------------------------------------
extern "C" void kernel_launch(void* const* d_in, const int* in_sizes, int n_in,
                              void* d_out, int out_size, void* d_ws, size_t ws_size,
                              hipStream_t stream) {
    const float* sub_id = (const float*)d_in[0];
    const float* W_sub  = (const float*)d_in[1];
    const float* b_sub  = (const float*)d_in[2];
    const float* W_fc   = (const float*)d_in[3];
    const float* b_fc   = (const float*)d_in[4];
    const float* bn_u0g = (const float*)d_in[5];
    const float* bn_u0b = (const float*)d_in[6];
    const float* up0_W  = (const float*)d_in[7];
    const float* up0_b  = (const float*)d_in[8];
    const float* bn_u1g = (const float*)d_in[9];
    const float* bn_u1b = (const float*)d_in[10];
    const float* up1_W  = (const float*)d_in[11];
    const float* up1_b  = (const float*)d_in[12];
    const float* bn0g   = (const float*)d_in[13];
    const float* bn0b   = (const float*)d_in[14];
    const float* c0_W   = (const float*)d_in[15];
    const float* c0_b   = (const float*)d_in[16];
    const float* bn1g   = (const float*)d_in[17];
    const float* bn1b   = (const float*)d_in[18];
    const float* c1_W   = (const float*)d_in[19];
    const float* c1_b   = (const float*)d_in[20];
    const float* bn2g   = (const float*)d_in[21];
    const float* bn2b   = (const float*)d_in[22];
    const float* c2_W   = (const float*)d_in[23];
    const float* c2_b   = (const float*)d_in[24];
    const int* neigh  = (const int*)d_in[25];
    const int* top0   = (const int*)d_in[26];
    const int* down0  = (const int*)d_in[27];
    const int* top1   = (const int*)d_in[28];
    const int* down1  = (const int*)d_in[29];

    float* ws = (float*)d_ws;
    // float-unit offsets; all 16B-aligned where vector-accessed
    float* y1p    = ws + 0;                   // 4096
    float* x0     = ws + 4096;                // 30726 fp32 -> ends 34822
    __half* xA_h  = (__half*)(ws + 34824);    // 40962*4 h = 81924 f -> ends 116748
    __half* xB_h  = (__half*)(ws + 116748);   // 163842*4 h = 327684 f -> ends 444432
    __half* h0_h  = (__half*)(ws + 444432);   // 163842*8 h = 655368 f -> ends 1099800
    __half* h1_h  = (__half*)(ws + 1099800);  // 163842*8 h = 655368 f -> ends 1755168
    float* slots  = ws + 1755168;             // 80 (5x16) + 256 bank floats

    float* st1 = slots + 16;
    float* st2 = slots + 32;
    float* st3 = slots + 48;
    float* st4 = slots + 64;
    float* bank0 = slots + 80;                // 16 banks x 16 floats

    const unsigned NB1 = (NV1 + 255) / 256;       // 161
    const unsigned NB2 = (NV2 + 255) / 256;       // 641
    const unsigned NBG2 = (3 * NV0 + 15) / 16;    // 1921

    k_gemv1<<<256 * SPLITK, 256, 0, stream>>>(sub_id, W_sub, y1p, slots);
    k_gemv2<<<NBG2, 256, 0, stream>>>(b_sub, y1p, W_fc, b_fc, x0, bank0);

    k_upconv<false, true><<<NB1, 256, 0, stream>>>(x0, NV0, NV1, bank0, st1,
                                                   bn_u0g, bn_u0b, up0_W, up0_b,
                                                   top0, down0, xA_h);
    k_upconv<true, false><<<NB2, 256, 0, stream>>>(xA_h, NV1, NV2, st1, st2,
                                                   bn_u1g, bn_u1b, up1_W, up1_b,
                                                   top1, down1, xB_h);

    k_onering<3, 8, true><<<NB2, 256, 0, stream>>>(
        xB_h, st2, st3, bn0g, bn0b, c0_W, c0_b, neigh, h0_h, nullptr);
    k_onering<8, 8, true><<<NB2, 256, 0, stream>>>(
        h0_h, st3, st4, bn1g, bn1b, c1_W, c1_b, neigh, h1_h, nullptr);
    k_onering<8, 2, false><<<NB2, 256, 0, stream>>>(
        h1_h, st4, nullptr, bn2g, bn2b, c2_W, c2_b, neigh, nullptr, (float*)d_out);
}